// Round 23
// baseline (62.055 us; speedup 1.0000x reference)
//
#include <hip/hip_runtime.h>
#include <math.h>

#define B 1024
#define E 256
#define H 4
#define DH 64
#define L 192
#define NF 16384
#define NO 49152
#define BPB 2   // batches per block

// ---------------------------------------------------------------------------
// Kernel 0 (prep): blocks 0..191 transpose Wq, Wv, Wo into WT; blocks 192..196
// compute per-batch start offsets by binary search.
// ---------------------------------------------------------------------------
__global__ __launch_bounds__(256) void prep_kernel(
    const int* __restrict__ fb, const int* __restrict__ ob,
    int* __restrict__ start_f, int* __restrict__ start_o,
    const float* __restrict__ ipw, const float* __restrict__ opw,
    float* __restrict__ WT)
{
  int blk = blockIdx.x;
  if (blk < 192) {
    int m = blk / 64;
    int r = blk % 64;
    int bx = (r & 7) * 32, by = (r >> 3) * 32;
    const float* src = (m == 0) ? ipw : (m == 1 ? ipw + 2 * E * E : opw);
    float* dst = WT + (size_t)m * E * E;
    __shared__ float tile[32][33];
    int tx = threadIdx.x & 31, ty = threadIdx.x >> 5;
#pragma unroll
    for (int i = 0; i < 32; i += 8)
      tile[ty + i][tx] = src[(size_t)(by + ty + i) * E + bx + tx];
    __syncthreads();
#pragma unroll
    for (int i = 0; i < 32; i += 8)
      dst[(size_t)(bx + ty + i) * E + by + tx] = tile[tx][ty + i];
  } else {
    int b = (blk - 192) * 256 + threadIdx.x;
    if (b > B) return;
    int lo = 0, hi = NF;
    while (lo < hi) { int m = (lo + hi) >> 1; if (fb[m] < b) lo = m + 1; else hi = m; }
    start_f[b] = lo;
    lo = 0; hi = NO;
    while (lo < hi) { int m = (lo + hi) >> 1; if (ob[m] < b) lo = m + 1; else hi = m; }
    start_o[b] = lo;
  }
}

// ---------------------------------------------------------------------------
// Fused kernel: 2 batches/block, 512 threads (8 waves), grid 512 (2 blocks/CU).
// LDS ~37 KB; un_s (16KB) time-multiplexed for q/Y/Z/ctx/out partials;
// YZ_s holds Y then Z. launch_bounds(512,2): no VGPR cap below ~256.
// Stream: wave = (batch bb, headpair hp, rowset rs); 2 heads/wave,
// rows s ≡ rs*4+g (mod 8); 2-way rowset merge in LDS.
// ---------------------------------------------------------------------------
__global__ __launch_bounds__(512, 2) void fused_kernel(
    const float* __restrict__ scene,
    const float* __restrict__ face, const float* __restrict__ obj,
    const float* __restrict__ ipw, const float* __restrict__ ipb,
    const float* __restrict__ WqT, const float* __restrict__ WvT,
    const float* __restrict__ WoT, const float* __restrict__ opb,
    const float* __restrict__ gamma, const float* __restrict__ beta,
    const int* __restrict__ start_f, const int* __restrict__ start_o,
    float* __restrict__ fusedO, float* __restrict__ attnw)
{
  int b0 = blockIdx.x * BPB;
  int t = threadIdx.x, wave = t >> 6, lane = t & 63;

  __shared__ float sc_s[BPB][E];       // 2 KB
  __shared__ float q_s[BPB][E];        // 2 KB (reused as x)
  __shared__ float YZ_s[BPB][H][E];    // 8 KB (Y, then Z)
  __shared__ float ctx_s[BPB][E];      // 2 KB
  __shared__ float s_s[BPB][H][L];     // 6 KB raw scores
  __shared__ float un_s[4096];         // 16 KB time-multiplexed partials
  __shared__ float mw_s[BPB][2][2][2], su_s[BPB][2][2][2], sb_s[BPB][H];
  __shared__ int   info_s[BPB][4];

  sc_s[t >> 8][t & 255] = scene[(size_t)b0 * E + t];   // BPB*E == 512
  if (t < BPB) {
    int b = b0 + t;
    int sf0 = start_f[b], cf = start_f[b + 1] - sf0;
    int so0 = start_o[b], co = start_o[b + 1] - so0;
    info_s[t][0] = sf0; info_s[t][1] = so0;
    info_s[t][2] = min(cf, L); info_s[t][3] = min(cf + co, L);
  }
  __syncthreads();

  // ---- q partials: wave covers j in [32w,32w+32); lane owns 4 outs ----
  {
    const float4* W4 = (const float4*)WqT + lane;
    float4 a0 = {0,0,0,0}, a1 = {0,0,0,0};
    int j0 = wave * 32;
#pragma unroll
    for (int jj = 0; jj < 32; ++jj) {
      int j = j0 + jj;
      float4 w = W4[(size_t)j * 64];
      float s0 = sc_s[0][j], s1 = sc_s[1][j];
      a0.x += s0*w.x; a0.y += s0*w.y; a0.z += s0*w.z; a0.w += s0*w.w;
      a1.x += s1*w.x; a1.y += s1*w.y; a1.z += s1*w.z; a1.w += s1*w.w;
    }
    *(float4*)&un_s[((wave * BPB + 0) << 8) + 4 * lane] = a0;
    *(float4*)&un_s[((wave * BPB + 1) << 8) + 4 * lane] = a1;
  }
  __syncthreads();
  {
    int bi = t >> 8, e = t & 255;      // BPB*E == 512
    float v = ipb[e];
#pragma unroll
    for (int w = 0; w < 8; ++w) v += un_s[((w * BPB + bi) << 8) + e];
    q_s[bi][e] = v;
  }
  __syncthreads();

  // ---- sb (waves 0..1, batch = wave) ----
  if (wave < BPB) {
#pragma unroll
    for (int h = 0; h < H; ++h) {
      float v = q_s[wave][h * DH + lane] * ipb[E + h * DH + lane];
#pragma unroll
      for (int o = 32; o; o >>= 1) v += __shfl_xor(v, o);
      if (lane == 0) sb_s[wave][h] = v;
    }
  }

  // ---- Y partials: wave -> (h = wave>>1, half wi = wave&1) ----
  {
    const float* Wk = ipw + (size_t)E * E;
    int h = wave >> 1, d0 = (wave & 1) * 32, wi = wave & 1;
    float4 a0 = {0,0,0,0}, a1 = {0,0,0,0};
#pragma unroll
    for (int dd = 0; dd < 32; ++dd) {
      int d = d0 + dd;
      float4 w = *((const float4*)(Wk + (size_t)(h * DH + d) * E) + lane);
      float q0 = q_s[0][h * DH + d], q1 = q_s[1][h * DH + d];
      a0.x += q0*w.x; a0.y += q0*w.y; a0.z += q0*w.z; a0.w += q0*w.w;
      a1.x += q1*w.x; a1.y += q1*w.y; a1.z += q1*w.z; a1.w += q1*w.w;
    }
    // Yp(wi, bi, h, e) = un_s[wi*2048 + ((bi*H+h)<<8) + e]
    *(float4*)&un_s[wi * 2048 + ((0 * H + h) << 8) + 4 * lane] = a0;
    *(float4*)&un_s[wi * 2048 + ((1 * H + h) << 8) + 4 * lane] = a1;
  }
  __syncthreads();
  for (int i = t; i < BPB * H * E; i += 512)
    ((float*)YZ_s)[i] = un_s[i] + un_s[2048 + i];
  __syncthreads();

  // ---- X-stream: wave = (bb = w>>2, hp = (w>>1)&1, rs = w&1) ----
  {
    int bb = wave >> 2, hp = (wave >> 1) & 1, rs = wave & 1, h0 = hp * 2;
    int g = lane >> 4, sl = lane & 15;
    int sf0 = info_s[bb][0], so0 = info_s[bb][1];
    int n_f = info_s[bb][2], n = info_s[bb][3];

    float4 y[2][4];
#pragma unroll
    for (int hh = 0; hh < 2; ++hh)
#pragma unroll
      for (int k = 0; k < 4; ++k)
        y[hh][k] = *(const float4*)&YZ_s[bb][h0 + hh][4 * (sl + 16 * k)];
    float sbv[2] = {sb_s[bb][h0], sb_s[bb][h0 + 1]};

    float m[2] = {-3.0e38f, -3.0e38f};
    float u[2] = {0.f, 0.f};
    float4 acc[2][4] = {};

    int s0 = rs * 4 + g;               // rows ≡ rs*4+g (mod 8)
    float4 x[4] = {};
    if (s0 < n) {
      const float* xr = (s0 < n_f) ? face + (size_t)(sf0 + s0) * E
                                   : obj  + (size_t)(so0 + s0 - n_f) * E;
#pragma unroll
      for (int k = 0; k < 4; ++k) x[k] = ((const float4*)xr)[sl + 16 * k];
    }

    for (int s = s0; s < n; s += 8) {
      float4 xn[4] = {};
      int sn = s + 8;
      if (sn < n) {
        const float* xr = (sn < n_f) ? face + (size_t)(sf0 + sn) * E
                                     : obj  + (size_t)(so0 + sn - n_f) * E;
#pragma unroll
        for (int k = 0; k < 4; ++k) xn[k] = ((const float4*)xr)[sl + 16 * k];
      }

      float p[2];
#pragma unroll
      for (int hh = 0; hh < 2; ++hh) {
        float a = 0.f;
#pragma unroll
        for (int k = 0; k < 4; ++k)
          a += x[k].x * y[hh][k].x + x[k].y * y[hh][k].y +
               x[k].z * y[hh][k].z + x[k].w * y[hh][k].w;
        p[hh] = a;
      }
#pragma unroll
      for (int off = 8; off; off >>= 1) {
        p[0] += __shfl_xor(p[0], off);
        p[1] += __shfl_xor(p[1], off);
      }
      p[0] = (p[0] + sbv[0]) * 0.125f;
      p[1] = (p[1] + sbv[1]) * 0.125f;
      if (sl == 0) {
        s_s[bb][h0][s] = p[0];
        s_s[bb][h0 + 1][s] = p[1];
      }
#pragma unroll
      for (int hh = 0; hh < 2; ++hh) {
        if (p[hh] > m[hh]) {
          float f = __expf(m[hh] - p[hh]);
#pragma unroll
          for (int k = 0; k < 4; ++k) {
            acc[hh][k].x = acc[hh][k].x * f + x[k].x;
            acc[hh][k].y = acc[hh][k].y * f + x[k].y;
            acc[hh][k].z = acc[hh][k].z * f + x[k].z;
            acc[hh][k].w = acc[hh][k].w * f + x[k].w;
          }
          u[hh] = u[hh] * f + 1.f;
          m[hh] = p[hh];
        } else {
          float e = __expf(p[hh] - m[hh]);
#pragma unroll
          for (int k = 0; k < 4; ++k) {
            acc[hh][k].x += e * x[k].x;
            acc[hh][k].y += e * x[k].y;
            acc[hh][k].z += e * x[k].z;
            acc[hh][k].w += e * x[k].w;
          }
          u[hh] += e;
        }
      }
#pragma unroll
      for (int k = 0; k < 4; ++k) x[k] = xn[k];
    }

    // merge 4 groups within the wave (xor 16, 32)
#pragma unroll
    for (int off = 16; off <= 32; off <<= 1) {
#pragma unroll
      for (int hh = 0; hh < 2; ++hh) {
        float mo = __shfl_xor(m[hh], off);
        float uo = __shfl_xor(u[hh], off);
        float M = fmaxf(m[hh], mo);
        float fs = __expf(m[hh] - M), fo = __expf(mo - M);
        u[hh] = fs * u[hh] + fo * uo;
        m[hh] = M;
#pragma unroll
        for (int k = 0; k < 4; ++k) {
          float ax = __shfl_xor(acc[hh][k].x, off);
          float ay = __shfl_xor(acc[hh][k].y, off);
          float az = __shfl_xor(acc[hh][k].z, off);
          float aw = __shfl_xor(acc[hh][k].w, off);
          acc[hh][k].x = fs * acc[hh][k].x + fo * ax;
          acc[hh][k].y = fs * acc[hh][k].y + fo * ay;
          acc[hh][k].z = fs * acc[hh][k].z + fo * az;
          acc[hh][k].w = fs * acc[hh][k].w + fo * aw;
        }
      }
    }
    // Zp(bb, hp, rs, hh, e) = un_s[(((bb*2+hp)*2+rs)*2+hh)<<8 + e]
    if (g == 0) {
#pragma unroll
      for (int hh = 0; hh < 2; ++hh)
#pragma unroll
        for (int k = 0; k < 4; ++k)
          *(float4*)&un_s[((((bb * 2 + hp) * 2 + rs) * 2 + hh) << 8) + 4 * (sl + 16 * k)] = acc[hh][k];
    }
    if (lane == 0) {
      mw_s[bb][hp][rs][0] = m[0]; mw_s[bb][hp][rs][1] = m[1];
      su_s[bb][hp][rs][0] = u[0]; su_s[bb][hp][rs][1] = u[1];
    }
  }
  __syncthreads();

  // ---- merge rowsets + normalize Z into YZ_s ----
  for (int i = t; i < BPB * H * E; i += 512) {
    int bi = i >> 10, rem = i & 1023, h = rem >> 8, e = rem & 255;
    float z = 0.f;
    if (info_s[bi][3] > 0) {
      int hp = h >> 1, hh = h & 1;
      float ma = mw_s[bi][hp][0][hh], mb = mw_s[bi][hp][1][hh];
      float M = fmaxf(ma, mb);
      float fa = __expf(ma - M), fb = __expf(mb - M);
      float inv = 1.0f / (fa * su_s[bi][hp][0][hh] + fb * su_s[bi][hp][1][hh]);
      z = (fa * un_s[((((bi * 2 + hp) * 2 + 0) * 2 + hh) << 8) + e] +
           fb * un_s[((((bi * 2 + hp) * 2 + 1) * 2 + hh) << 8) + e]) * inv;
    }
    ((float*)YZ_s)[i] = z;
  }
  // ---- attnw (BPB*L = 384 <= 512) ----
  if (t < BPB * L) {
    int bi = t / L, s = t - bi * L;
    int n = info_s[bi][3];
    float v;
    if (n == 0) v = 1.0f / L;
    else if (s < n) {
      v = 0.f;
#pragma unroll
      for (int h = 0; h < H; ++h) {
        int hp = h >> 1, hh = h & 1;
        float ma = mw_s[bi][hp][0][hh], mb = mw_s[bi][hp][1][hh];
        float M = fmaxf(ma, mb);
        float fa = __expf(ma - M), fb = __expf(mb - M);
        float inv = 1.0f / (fa * su_s[bi][hp][0][hh] + fb * su_s[bi][hp][1][hh]);
        v += __expf(s_s[bi][h][s] - M) * inv;
      }
      v *= 0.25f;
    } else v = 0.f;
    attnw[(size_t)(b0 + bi) * L + s] = v;
  }
  __syncthreads();

  // ---- ctx partials: wave covers j in [32w,32w+32); head(4l..) = l>>4 ----
  {
    const float4* W4 = (const float4*)WvT + lane;
    int j0 = wave * 32, hoff = (lane >> 4) * E;
    float4 a0 = {0,0,0,0}, a1 = {0,0,0,0};
#pragma unroll
    for (int jj = 0; jj < 32; ++jj) {
      int j = j0 + jj;
      float4 w = W4[(size_t)j * 64];
      float z0 = ((float*)YZ_s[0])[hoff + j];
      float z1 = ((float*)YZ_s[1])[hoff + j];
      a0.x += z0*w.x; a0.y += z0*w.y; a0.z += z0*w.z; a0.w += z0*w.w;
      a1.x += z1*w.x; a1.y += z1*w.y; a1.z += z1*w.z; a1.w += z1*w.w;
    }
    *(float4*)&un_s[((wave * BPB + 0) << 8) + 4 * lane] = a0;
    *(float4*)&un_s[((wave * BPB + 1) << 8) + 4 * lane] = a1;
  }
  __syncthreads();
  {
    int bi = t >> 8, e = t & 255;
    float v = ipb[2 * E + e];
#pragma unroll
    for (int w = 0; w < 8; ++w) v += un_s[((w * BPB + bi) << 8) + e];
    ctx_s[bi][e] = v;
  }
  __syncthreads();

  // ---- out-proj partials ----
  {
    const float4* W4 = (const float4*)WoT + lane;
    int j0 = wave * 32;
    float4 a0 = {0,0,0,0}, a1 = {0,0,0,0};
#pragma unroll
    for (int jj = 0; jj < 32; ++jj) {
      int j = j0 + jj;
      float4 w = W4[(size_t)j * 64];
      float c0 = ctx_s[0][j], c1 = ctx_s[1][j];
      a0.x += c0*w.x; a0.y += c0*w.y; a0.z += c0*w.z; a0.w += c0*w.w;
      a1.x += c1*w.x; a1.y += c1*w.y; a1.z += c1*w.z; a1.w += c1*w.w;
    }
    *(float4*)&un_s[((wave * BPB + 0) << 8) + 4 * lane] = a0;
    *(float4*)&un_s[((wave * BPB + 1) << 8) + 4 * lane] = a1;
  }
  __syncthreads();
  {
    int bi = t >> 8, e = t & 255;
    float v = opb[e] + sc_s[bi][e];
#pragma unroll
    for (int w = 0; w < 8; ++w) v += un_s[((w * BPB + bi) << 8) + e];
    q_s[bi][e] = v;                    // reuse q_s as x
  }
  __syncthreads();

  // ---- LayerNorm: waves 0..1, one batch each ----
  if (wave < BPB) {
    float v0 = q_s[wave][lane], v1 = q_s[wave][lane + 64],
          v2 = q_s[wave][lane + 128], v3 = q_s[wave][lane + 192];
    float s1 = v0 + v1 + v2 + v3;
#pragma unroll
    for (int o = 32; o; o >>= 1) s1 += __shfl_xor(s1, o);
    float mu = s1 * (1.0f / E);
    float d0 = v0 - mu, d1 = v1 - mu, d2 = v2 - mu, d3 = v3 - mu;
    float s2 = d0*d0 + d1*d1 + d2*d2 + d3*d3;
#pragma unroll
    for (int o = 32; o; o >>= 1) s2 += __shfl_xor(s2, o);
    float inv = 1.0f / sqrtf(s2 * (1.0f / E) + 1e-5f);
    size_t base = (size_t)(b0 + wave) * E;
    fusedO[base + lane      ] = d0 * inv * gamma[lane      ] + beta[lane      ];
    fusedO[base + lane +  64] = d1 * inv * gamma[lane +  64] + beta[lane +  64];
    fusedO[base + lane + 128] = d2 * inv * gamma[lane + 128] + beta[lane + 128];
    fusedO[base + lane + 192] = d3 * inv * gamma[lane + 192] + beta[lane + 192];
  }
}

// ---------------------------------------------------------------------------
extern "C" void kernel_launch(void* const* d_in, const int* in_sizes, int n_in,
                              void* d_out, int out_size, void* d_ws, size_t ws_size,
                              hipStream_t stream) {
  const float* scene = (const float*)d_in[0];
  const float* face  = (const float*)d_in[1];
  const float* obj   = (const float*)d_in[2];
  const int*   fb    = (const int*)d_in[3];
  const int*   ob    = (const int*)d_in[4];
  const float* ipw   = (const float*)d_in[5];
  const float* ipb   = (const float*)d_in[6];
  const float* opw   = (const float*)d_in[7];
  const float* opb   = (const float*)d_in[8];
  const float* gam   = (const float*)d_in[9];
  const float* bet   = (const float*)d_in[10];

  float* fused = (float*)d_out;
  float* attnw = fused + (size_t)B * E;

  // ws: starts (16KB) | WT (768KB)
  int* start_f = (int*)d_ws;
  int* start_o = start_f + (B + 1);
  float* WT   = (float*)((char*)d_ws + (16 << 10));
  float* WqT = WT;
  float* WvT = WT + (size_t)E * E;
  float* WoT = WT + (size_t)2 * E * E;

  prep_kernel<<<197, 256, 0, stream>>>(fb, ob, start_f, start_o, ipw, opw, WT);
  fused_kernel<<<B / BPB, 512, 0, stream>>>(scene, face, obj, ipw, ipb,
                                            WqT, WvT, WoT, opb, gam, bet,
                                            start_f, start_o, fused, attnw);
}